// Round 19
// baseline (132.393 us; speedup 1.0000x reference)
//
#include <hip/hip_runtime.h>
#include <hip/hip_bf16.h>

#define NDIGIT 10
#define DIM_IN 256
#define DIM_OUT 784
#define BATCH 16384
#define NCT 49                            // 784/16 col-tiles
#define TM32 32                           // rows per block
#define MAX_T32 (BATCH / TM32 + NDIGIT)   // 522 worst-case 32-row tiles
#define RBSS 792                          // rowbuf SHORT stride (784+8)

// ws layout:
//  ints [0..10]     bucket row offsets[11]
//  ints [24]        total 32-row tiles
//  ints [64 + j*16 + g]   per-hist-block partial counts (j<32, g<10)
//  ints [1024..17407]     idx[16384]
//  ints [17408..17929]    per-tile desc: startRow | rc<<14 | g<<21
//  byte 81920..           W bf16 FRAG-PACKED: [g][ct:49][ks:8][lane:64][8]
//  byte 4,096,000..       thsort bf16 (16384 x 256, sorted by label)
#define WS_IDX 1024
#define WS_DESC 17408
#define WS_WBF_BYTES 81920
#define WS_TH_BYTES (WS_WBF_BYTES + 2007040 * 2)   // 4,096,000
#define WS_NEED (WS_TH_BYTES + BATCH * DIM_IN * 2) // 12,484,608

typedef __attribute__((ext_vector_type(4))) float f32x4;
typedef __attribute__((ext_vector_type(8))) short bf16x8;
typedef __attribute__((ext_vector_type(4))) unsigned short u16x4;

__device__ __forceinline__ short f2bf(float f) {
    union { float f; unsigned u; } c; c.f = f;
    unsigned u = c.u;
    u += 0x7fffu + ((u >> 16) & 1u);   // RNE
    return (short)(u >> 16);
}

__device__ __forceinline__ void gload16(const void* gp, void* lp) {
    __builtin_amdgcn_global_load_lds(
        (const __attribute__((address_space(1))) void*)gp,
        (__attribute__((address_space(3))) void*)lp, 16, 0, 0);
}

// tiny: label histogram partials only (32 blocks x 256)
__global__ void hist_k(const int* __restrict__ label, int* __restrict__ wsi) {
    __shared__ int h[NDIGIT];
    int j = blockIdx.x, t = threadIdx.x;
    if (t < NDIGIT) h[t] = 0;
    __syncthreads();
    int i0 = j * 512;
    atomicAdd(&h[label[i0 + t]], 1);
    atomicAdd(&h[label[i0 + 256 + t]], 1);
    __syncthreads();
    if (t < NDIGIT) wsi[64 + j * 16 + t] = h[t];
}

// 32 blocks x 512 threads; block j owns rows [j*512, j*512+512).
// Block 0 also builds bucket offsets and the 32-row-tile desc table.
__global__ void scatter2_k(const int* __restrict__ label, int* __restrict__ wsi) {
    __shared__ int tot[NDIGIT], bef[NDIGIT], base[NDIGIT + 1], cur[NDIGIT], toff[NDIGIT + 1];
    int j = blockIdx.x, t = threadIdx.x;
    if (t < NDIGIT) {
        int s = 0, sb = 0;
        for (int jj = 0; jj < 32; ++jj) {
            int v = wsi[64 + jj * 16 + t];
            s += v;
            if (jj < j) sb += v;
        }
        tot[t] = s; bef[t] = sb;
    }
    __syncthreads();
    if (t == 0) {
        int off = 0, tf = 0;
        for (int g = 0; g < NDIGIT; ++g) {
            base[g] = off; toff[g] = tf;
            off += tot[g]; tf += (tot[g] + TM32 - 1) / TM32;
        }
        base[NDIGIT] = off; toff[NDIGIT] = tf;
    }
    __syncthreads();
    if (t < NDIGIT) cur[t] = base[t] + bef[t];
    if (j == 0) {
        int ptotal = toff[NDIGIT];
        for (int p = t; p < ptotal; p += 512) {
            int g2 = 0;
            while (p >= toff[g2 + 1]) ++g2;
            int row0 = (p - toff[g2]) * TM32;
            int rcv = tot[g2] - row0; if (rcv > TM32) rcv = TM32;
            wsi[WS_DESC + p] = (base[g2] + row0) | (rcv << 14) | (g2 << 21);
        }
        if (t < NDIGIT) wsi[t] = base[t];
        if (t == 0) { wsi[10] = base[NDIGIT]; wsi[24] = ptotal; }
    }
    __syncthreads();
    int i = j * 512 + t;
    int g = label[i];
    int r = atomicAdd(&cur[g], 1);
    wsi[WS_IDX + r] = i;
}

// fused: blocks [0,2048) gather theta->thsort (bf16, sorted order);
//        blocks [2048,3028) pack megaW f32->bf16 in MFMA-fragment order.
__global__ void gw_k(const float* __restrict__ theta,
                     const float* __restrict__ megaW,
                     const int* __restrict__ wsi,
                     short* __restrict__ thsort,
                     short* __restrict__ wbf) {
    int b = blockIdx.x, t = threadIdx.x;
    if (b < 2048) {
        int gid = b * 256 + t;
        int r = gid >> 5;
        int c8 = (gid & 31) << 3;
        int src = wsi[WS_IDX + r];
        const float* p = theta + (size_t)src * DIM_IN + c8;
        f32x4 v0 = *(const f32x4*)p;
        f32x4 v1 = *(const f32x4*)(p + 4);
        bf16x8 o;
        o[0] = f2bf(v0[0]); o[1] = f2bf(v0[1]); o[2] = f2bf(v0[2]); o[3] = f2bf(v0[3]);
        o[4] = f2bf(v1[0]); o[5] = f2bf(v1[1]); o[6] = f2bf(v1[2]); o[7] = f2bf(v1[3]);
        *(bf16x8*)(thsort + (size_t)r * DIM_IN + c8) = o;
    } else {
        int idx = (b - 2048) * 256 + t;   // 0..250879 = 490*8*64
        int gi = idx >> 9;                // g*49 + ct
        int ks = (idx >> 6) & 7;
        int l  = idx & 63;
        int g  = gi / 49;
        int ct = gi - g * 49;
        int col = ct * 16 + (l & 15);
        int k   = ks * 32 + ((l >> 4) << 3);
        const float* src = megaW + ((size_t)(g * DIM_OUT + col) * DIM_IN + k);
        f32x4 v0 = *(const f32x4*)src;
        f32x4 v1 = *(const f32x4*)(src + 4);
        bf16x8 o;
        o[0] = f2bf(v0[0]); o[1] = f2bf(v0[1]); o[2] = f2bf(v0[2]); o[3] = f2bf(v0[3]);
        o[4] = f2bf(v1[0]); o[5] = f2bf(v1[1]); o[6] = f2bf(v1[2]); o[7] = f2bf(v1[3]);
        *(bf16x8*)(wbf + (size_t)idx * 8) = o;
    }
}

// gemm19: one block = 32 sorted rows x FULL 784 cols (line-complete stores),
// 8 waves; wave wv owns ct = wv, wv+8, ... with 2-deep B prefetch; each
// B-frag feeds TWO MFMAs (both 16-row halves -> register B reuse); sigmoid
// -> bf16 rowbuf -> cooperative contiguous full-tile f32 stores.

#define LOADB19(B, CT) do {                                                    \
    const short* Bt_ = Wg + (size_t)(CT) * 4096 + l * 8;                       \
    _Pragma("unroll")                                                          \
    for (int ks = 0; ks < 8; ++ks)                                             \
        (B)[ks] = *(const bf16x8*)(Bt_ + ks * 512);                            \
} while (0)

#define TILE19(B, CT) do {                                                     \
    float bias_ = bgb[(CT) * 16 + r16];                                        \
    f32x4 A0_ = {0.f, 0.f, 0.f, 0.f}, A1_ = {0.f, 0.f, 0.f, 0.f};             \
    _Pragma("unroll")                                                          \
    for (int ks = 0; ks < 8; ++ks) {                                           \
        A0_ = __builtin_amdgcn_mfma_f32_16x16x32_bf16(a0[ks], (B)[ks], A0_, 0, 0, 0); \
        A1_ = __builtin_amdgcn_mfma_f32_16x16x32_bf16(a1[ks], (B)[ks], A1_, 0, 0, 0); \
    }                                                                          \
    _Pragma("unroll")                                                          \
    for (int j = 0; j < 4; ++j) {                                              \
        float x0_ = A0_[j] + bias_;                                            \
        float x1_ = A1_[j] + bias_;                                            \
        rowbuf[(kg * 4 + j) * RBSS + (CT) * 16 + r16] =                        \
            f2bf(1.0f / (1.0f + __expf(-x0_)));                                \
        rowbuf[(16 + kg * 4 + j) * RBSS + (CT) * 16 + r16] =                   \
            f2bf(1.0f / (1.0f + __expf(-x1_)));                                \
    }                                                                          \
} while (0)

__launch_bounds__(512, 6)   // 6 waves/SIMD = 3 blocks/CU cap (512-thr blocks)
__global__ void moe_gemm19_k(const short* __restrict__ thsort,
                             const float* __restrict__ megab,
                             const int* __restrict__ wsi,
                             const short* __restrict__ wbf,
                             float* __restrict__ out) {
    __shared__ short rowbuf[TM32 * RBSS];   // 50688 B

    int Bid = blockIdx.x;
    const int q8 = MAX_T32 / 8, r8 = MAX_T32 % 8;   // 65, 2
    int xcd = Bid & 7, slot = Bid >> 3;
    int p = (xcd < r8 ? xcd * (q8 + 1) : r8 * (q8 + 1) + (xcd - r8) * q8) + slot;

    int total = wsi[24];
    if (p >= total) return;               // uniform exit before the barrier

    int d = wsi[WS_DESC + p];
    int startRow = d & 0x3FFF;
    int rc = (d >> 14) & 0x7F;
    int g  = d >> 21;

    int tid = threadIdx.x;
    int wv = tid >> 6, l = tid & 63, r16 = l & 15, kg = l >> 4;

    // ---- A fragments: both 16-row halves (identical across waves; L1-hit)
    int m0 = r16;      if (m0 >= rc) m0 = rc - 1;
    int m1 = 16 + r16; if (m1 >= rc) m1 = rc - 1;
    const short* Ar0 = thsort + (size_t)(startRow + m0) * DIM_IN + kg * 8;
    const short* Ar1 = thsort + (size_t)(startRow + m1) * DIM_IN + kg * 8;
    bf16x8 a0[8], a1[8];
#pragma unroll
    for (int ks = 0; ks < 8; ++ks) {
        a0[ks] = *(const bf16x8*)(Ar0 + ks * 32);
        a1[ks] = *(const bf16x8*)(Ar1 + ks * 32);
    }

    const short* Wg  = wbf + (size_t)g * (NCT * 4096);
    const float* bgb = megab + (size_t)g * DIM_OUT;

    // ---- col-tile loop with 2-deep B prefetch; wave wv owns ct = wv, wv+8, ...
    bf16x8 bA[8], bB[8];
    int ct = wv;
    LOADB19(bA, ct);
    while (true) {
        int c1 = ct + 8;
        if (c1 < NCT) { LOADB19(bB, c1); TILE19(bA, ct); }
        else          { TILE19(bA, ct); break; }
        int c2 = c1 + 8;
        if (c2 < NCT) { LOADB19(bA, c2); TILE19(bB, c1); }
        else          { TILE19(bB, c1); break; }
        ct = c2;
    }

    __syncthreads();                      // rowbuf complete

    // ---- cooperative contiguous stores: 32 rows x 3136 B (line-complete)
    const int* idxl = wsi + WS_IDX + startRow;
#pragma unroll
    for (int s = 0; s < 13; ++s) {
        int c = s * 512 + tid;            // 0..6655; 6272 = 32 rows x 196 chunks
        if (c < TM32 * 196) {
            int row = c / 196;
            int cir = c - row * 196;
            if (row < rc) {
                u16x4 v = *(const u16x4*)(rowbuf + row * RBSS + cir * 4);
                union { unsigned u; float f; } c0, c1, c2, c3;
                c0.u = (unsigned)v[0] << 16;
                c1.u = (unsigned)v[1] << 16;
                c2.u = (unsigned)v[2] << 16;
                c3.u = (unsigned)v[3] << 16;
                f32x4 o = { c0.f, c1.f, c2.f, c3.f };
                *(f32x4*)(out + (size_t)idxl[row] * DIM_OUT + cir * 4) = o;
            }
        }
    }
}

// =============== fallback path (small ws): r4-proven =====================
__global__ void prep_k(const float* __restrict__ megaW,
                       const int* __restrict__ label,
                       int* __restrict__ wsi,
                       short* __restrict__ wbf) {
    int b = blockIdx.x, t = threadIdx.x;
    if (b < 980) {
        int base = b * 2048 + t * 8;
        f32x4 v0 = *(const f32x4*)(megaW + base);
        f32x4 v1 = *(const f32x4*)(megaW + base + 4);
        bf16x8 o;
        o[0] = f2bf(v0[0]); o[1] = f2bf(v0[1]); o[2] = f2bf(v0[2]); o[3] = f2bf(v0[3]);
        o[4] = f2bf(v1[0]); o[5] = f2bf(v1[1]); o[6] = f2bf(v1[2]); o[7] = f2bf(v1[3]);
        *(bf16x8*)(wbf + base) = o;      // row-major for fallback gemm
    } else {
        __shared__ int h[NDIGIT];
        int j = b - 980;
        if (t < NDIGIT) h[t] = 0;
        __syncthreads();
        int i0 = j * 512;
        atomicAdd(&h[label[i0 + t]], 1);
        atomicAdd(&h[label[i0 + 256 + t]], 1);
        __syncthreads();
        if (t < NDIGIT) wsi[64 + j * 16 + t] = h[t];
    }
}

// fallback scan/scatter (r1-proven semantics) writing 64-row tile offsets
__global__ void fscan_k(int* __restrict__ wsi) {
    int off = 0, toff = 0;
    for (int g = 0; g < NDIGIT; ++g) {
        int tot = 0;
        for (int jj = 0; jj < 32; ++jj) tot += wsi[64 + jj * 16 + g];
        wsi[g] = off;
        wsi[40 + g] = toff;
        off += tot;
        toff += (tot + 63) / 64;
    }
    wsi[10] = off; wsi[50] = toff; wsi[24] = toff;
}

__global__ void fscatter_k(const int* __restrict__ label, int* __restrict__ wsi) {
    __shared__ int lc[NDIGIT], lb[NDIGIT];
    int t = threadIdx.x;
    if (t < NDIGIT) lc[t] = 0;
    __syncthreads();
    int i = blockIdx.x * 256 + t;
    int g = label[i];
    int r = atomicAdd(&lc[g], 1);
    __syncthreads();
    if (t < NDIGIT) lb[t] = (lc[t] > 0) ? atomicAdd(&wsi[52 + t], lc[t]) : 0;
    __syncthreads();
    wsi[WS_IDX + wsi[g] + lb[g] + r] = i;
}

__launch_bounds__(256, 4)
__global__ void moe_gemmF_k(const float* __restrict__ theta,
                            const float* __restrict__ megab,
                            const int* __restrict__ wsi,
                            const short* __restrict__ wbf,
                            float* __restrict__ out) {
    __shared__ short Bsf[112 * 128];
    int Bid = blockIdx.x;
    int mt = Bid / 7, cb = Bid % 7;
    int total = wsi[24];
    if (mt >= total) return;
    int g = 0;
    while (mt >= wsi[40 + g + 1]) ++g;
    int lt    = mt - wsi[40 + g];
    int start = wsi[g];
    int cnt   = wsi[g + 1] - start;
    int row0  = lt * 64;
    int rc    = min(64, cnt - row0);
    int tid = threadIdx.x;
    int wv = tid >> 6, l = tid & 63, r16 = l & 15, kg = l >> 4;
    const char* Wcb = (const char*)(wbf + ((size_t)g * DIM_OUT + (size_t)cb * 112) * DIM_IN);
#pragma unroll
    for (int it = 0; it < 7; ++it) {
        int lbyte = (it * 256 + tid) << 4;
        int L = lbyte ^ (((lbyte >> 8) & 7) << 4);
        int srcoff = ((L >> 8) << 9) + (L & 255);
        gload16(Wcb + srcoff, (char*)Bsf + lbyte);
    }
    const int* idxlist = wsi + WS_IDX + start + row0;
    int mloc = wv * 16 + r16;
    int asrc = (mloc < rc) ? idxlist[mloc] : idxlist[0];
    const float* Arow = theta + (size_t)asrc * DIM_IN;
    bf16x8 a[8];
#pragma unroll
    for (int ks = 0; ks < 8; ++ks) {
        int k0 = ks * 32 + kg * 8;
        f32x4 v0 = *(const f32x4*)(Arow + k0);
        f32x4 v1 = *(const f32x4*)(Arow + k0 + 4);
        bf16x8 af;
        af[0] = f2bf(v0[0]); af[1] = f2bf(v0[1]);
        af[2] = f2bf(v0[2]); af[3] = f2bf(v0[3]);
        af[4] = f2bf(v1[0]); af[5] = f2bf(v1[1]);
        af[6] = f2bf(v1[2]); af[7] = f2bf(v1[3]);
        a[ks] = af;
    }
    f32x4 acc[7];
#pragma unroll
    for (int ns = 0; ns < 7; ++ns) acc[ns] = (f32x4){0.f, 0.f, 0.f, 0.f};
    __syncthreads();
#pragma unroll
    for (int ks = 0; ks < 4; ++ks)
#pragma unroll
        for (int ns = 0; ns < 7; ++ns) {
            int n = ns * 16 + r16;
            int byte = (n << 8) + (ks << 6) + (kg << 4);
            byte ^= (n & 7) << 4;
            bf16x8 b = *(const bf16x8*)((const char*)Bsf + byte);
            acc[ns] = __builtin_amdgcn_mfma_f32_16x16x32_bf16(a[ks], b, acc[ns], 0, 0, 0);
        }
    __syncthreads();
#pragma unroll
    for (int it = 0; it < 7; ++it) {
        int lbyte = (it * 256 + tid) << 4;
        int L = lbyte ^ (((lbyte >> 8) & 7) << 4);
        int srcoff = ((L >> 8) << 9) + (L & 255) + 256;
        gload16(Wcb + srcoff, (char*)Bsf + lbyte);
    }
    __syncthreads();
#pragma unroll
    for (int ks = 0; ks < 4; ++ks)
#pragma unroll
        for (int ns = 0; ns < 7; ++ns) {
            int n = ns * 16 + r16;
            int byte = (n << 8) + (ks << 6) + (kg << 4);
            byte ^= (n & 7) << 4;
            bf16x8 b = *(const bf16x8*)((const char*)Bsf + byte);
            acc[ns] = __builtin_amdgcn_mfma_f32_16x16x32_bf16(a[4 + ks], b, acc[ns], 0, 0, 0);
        }
    const float* bg = megab + (size_t)g * DIM_OUT + (size_t)cb * 112;
    int rbase = wv * 16 + kg * 4;
    int orow[4];
#pragma unroll
    for (int j = 0; j < 4; ++j)
        orow[j] = (rbase + j < rc) ? idxlist[rbase + j] : -1;
#pragma unroll
    for (int ns = 0; ns < 7; ++ns) {
        int nloc = ns * 16 + r16;
        float bias = bg[nloc];
#pragma unroll
        for (int j = 0; j < 4; ++j) {
            if (orow[j] >= 0) {
                float x = acc[ns][j] + bias;
                out[(size_t)orow[j] * DIM_OUT + cb * 112 + nloc] = 1.0f / (1.0f + __expf(-x));
            }
        }
    }
}

extern "C" void kernel_launch(void* const* d_in, const int* in_sizes, int n_in,
                              void* d_out, int out_size, void* d_ws, size_t ws_size,
                              hipStream_t stream) {
    const float* theta = (const float*)d_in[0];
    const int*   label = (const int*)d_in[1];
    const float* megaW = (const float*)d_in[2];
    const float* megab = (const float*)d_in[3];
    float* out = (float*)d_out;
    int* wsi = (int*)d_ws;
    short* wbf = (short*)((char*)d_ws + WS_WBF_BYTES);

    if (ws_size >= (size_t)WS_NEED) {
        short* thsort = (short*)((char*)d_ws + WS_TH_BYTES);
        hist_k      <<<32, 256, 0, stream>>>(label, wsi);
        scatter2_k  <<<32, 512, 0, stream>>>(label, wsi);
        gw_k        <<<3028, 256, 0, stream>>>(theta, megaW, wsi, thsort, wbf);
        moe_gemm19_k<<<MAX_T32, 512, 0, stream>>>(thsort, megab, wsi, wbf, out);
    } else {
        hipMemsetAsync((char*)d_ws + 52 * 4, 0, 10 * 4, stream);
        prep_k     <<<1012, 256, 0, stream>>>(megaW, label, wsi, wbf);
        fscan_k    <<<1, 1, 0, stream>>>(wsi);
        fscatter_k <<<64, 256, 0, stream>>>(label, wsi);
        moe_gemmF_k<<<274 * 7, 256, 0, stream>>>(theta, megab, wsi, wbf, out);
    }
}

// Round 20
// 42.851 us; speedup vs baseline: 3.0896x; 3.0896x over previous
//
#include <hip/hip_runtime.h>
#include <hip/hip_bf16.h>

#define NDIGIT 10
#define DIM_IN 256
#define DIM_OUT 784
#define BATCH 16384
#define BM 64                           // rows per block (4 waves x 16)
#define BN 112                          // cols per block (7 x 16)
#define NCB 7                           // 784 / 112
#define MAX_MT (BATCH / BM + NDIGIT)    // 266 worst-case 64-row tiles
#define G_BLOCKS (MAX_MT * NCB)         // 1862
#define QB 14336                        // one K-quarter: 112 rows x 128 B
#define RBSTRIDE 116                    // rowbuf row stride (dwords)
#define LDS_BYTES 29696                 // max(2*QB, 4 waves*16*116*4)

// ws layout:
//  ints [0..10]    bucket row offsets[11]
//  ints [12..22]   64-row tile offsets[11] (fallback)
//  ints [24]       total 64-row tiles
//  ints [64 + j*16 + g]  per-hist-block partial counts (j<32, g<10)
//  ints [600..875] per-tile desc: startRow | rc<<14 | g<<21
//  ints [1024..17407]    idx[16384]
//  byte 69632..           W bf16 row-major (2,007,040 shorts)
//  byte 4,083,712..       thsort bf16 (16384 x 256, sorted by label)
#define WS_IDX 1024
#define WS_DESC 600
#define WS_WBF_BYTES 69632
#define WS_TH_BYTES (WS_WBF_BYTES + 2007040 * 2)   // 4,083,712
#define WS_NEED (WS_TH_BYTES + BATCH * DIM_IN * 2) // 12,472,320

typedef __attribute__((ext_vector_type(4))) float f32x4;
typedef __attribute__((ext_vector_type(8))) short bf16x8;

__device__ __forceinline__ short f2bf(float f) {
    union { float f; unsigned u; } c; c.f = f;
    unsigned u = c.u;
    u += 0x7fffu + ((u >> 16) & 1u);   // RNE
    return (short)(u >> 16);
}

__device__ __forceinline__ void gload16(const void* gp, void* lp) {
    __builtin_amdgcn_global_load_lds(
        (const __attribute__((address_space(1))) void*)gp,
        (__attribute__((address_space(3))) void*)lp, 16, 0, 0);
}

// tiny: label histogram partials only (32 blocks x 256)
__global__ void hist_k(const int* __restrict__ label, int* __restrict__ wsi) {
    __shared__ int h[NDIGIT];
    int j = blockIdx.x, t = threadIdx.x;
    if (t < NDIGIT) h[t] = 0;
    __syncthreads();
    int i0 = j * 512;
    atomicAdd(&h[label[i0 + t]], 1);
    atomicAdd(&h[label[i0 + 256 + t]], 1);
    __syncthreads();
    if (t < NDIGIT) wsi[64 + j * 16 + t] = h[t];
}

// 32 blocks x 512 threads; block j owns rows [j*512, j*512+512).
// Block 0 also builds bucket offsets, tile offsets, and the desc table.
__global__ void scatter2_k(const int* __restrict__ label, int* __restrict__ wsi) {
    __shared__ int tot[NDIGIT], bef[NDIGIT], base[NDIGIT + 1], cur[NDIGIT], toff[NDIGIT + 1];
    int j = blockIdx.x, t = threadIdx.x;
    if (t < NDIGIT) {
        int s = 0, sb = 0;
        for (int jj = 0; jj < 32; ++jj) {
            int v = wsi[64 + jj * 16 + t];
            s += v;
            if (jj < j) sb += v;
        }
        tot[t] = s; bef[t] = sb;
    }
    __syncthreads();
    if (t == 0) {
        int off = 0, tf = 0;
        for (int g = 0; g < NDIGIT; ++g) {
            base[g] = off; toff[g] = tf;
            off += tot[g]; tf += (tot[g] + BM - 1) / BM;
        }
        base[NDIGIT] = off; toff[NDIGIT] = tf;
    }
    __syncthreads();
    if (t < NDIGIT) cur[t] = base[t] + bef[t];
    if (j == 0) {
        int ptotal = toff[NDIGIT];
        for (int p = t; p < ptotal; p += 512) {
            int g2 = 0;
            while (p >= toff[g2 + 1]) ++g2;
            int row0 = (p - toff[g2]) * BM;
            int rcv = tot[g2] - row0; if (rcv > BM) rcv = BM;
            wsi[WS_DESC + p] = (base[g2] + row0) | (rcv << 14) | (g2 << 21);
        }
        if (t < NDIGIT) { wsi[t] = base[t]; wsi[12 + t] = toff[t]; }
        if (t == 0) {
            wsi[10] = base[NDIGIT]; wsi[22] = toff[NDIGIT]; wsi[24] = toff[NDIGIT];
        }
    }
    __syncthreads();
    int i = j * 512 + t;
    int g = label[i];
    int r = atomicAdd(&cur[g], 1);
    wsi[WS_IDX + r] = i;
}

// fused: blocks [0,2048) gather theta->thsort (bf16, sorted order);
//        blocks [2048,3028) convert megaW f32->bf16 row-major.
__global__ void gw_k(const float* __restrict__ theta,
                     const float* __restrict__ megaW,
                     const int* __restrict__ wsi,
                     short* __restrict__ thsort,
                     short* __restrict__ wbf) {
    int b = blockIdx.x, t = threadIdx.x;
    if (b < 2048) {
        int gid = b * 256 + t;
        int r = gid >> 5;
        int c8 = (gid & 31) << 3;
        int src = wsi[WS_IDX + r];
        const float* p = theta + (size_t)src * DIM_IN + c8;
        f32x4 v0 = *(const f32x4*)p;
        f32x4 v1 = *(const f32x4*)(p + 4);
        bf16x8 o;
        o[0] = f2bf(v0[0]); o[1] = f2bf(v0[1]); o[2] = f2bf(v0[2]); o[3] = f2bf(v0[3]);
        o[4] = f2bf(v1[0]); o[5] = f2bf(v1[1]); o[6] = f2bf(v1[2]); o[7] = f2bf(v1[3]);
        *(bf16x8*)(thsort + (size_t)r * DIM_IN + c8) = o;
    } else {
        int base = (b - 2048) * 2048 + t * 8;   // 980*2048 = 2,007,040 exact
        f32x4 v0 = *(const f32x4*)(megaW + base);
        f32x4 v1 = *(const f32x4*)(megaW + base + 4);
        bf16x8 o;
        o[0] = f2bf(v0[0]); o[1] = f2bf(v0[1]); o[2] = f2bf(v0[2]); o[3] = f2bf(v0[3]);
        o[4] = f2bf(v1[0]); o[5] = f2bf(v1[1]); o[6] = f2bf(v1[2]); o[7] = f2bf(v1[3]);
        *(bf16x8*)(wbf + base) = o;
    }
}

// stage K-quarter q (112 rows x 128 B) into linear LDS; source pre-swizzled
// (r9 layout: measured 0 bank conflicts).
__device__ __forceinline__ void stage_q(const char* Wcb, int q, char* Bq, int tid) {
#pragma unroll
    for (int it = 0; it < 4; ++it) {
        int chunk = it * 256 + tid;            // 0..1023 (896 real)
        if (chunk >= 896) chunk -= 128;        // dup tail, benign
        int lbyte = chunk << 4;
        int L = lbyte ^ ((((lbyte >> 7) & 7)) << 4);   // involution
        int row = L >> 7, koff = L & 127;
        gload16(Wcb + row * 512 + q * 128 + koff, Bq + lbyte);
    }
}

#define COMPUTE_Q(Q, BUF) do {                                                 \
    _Pragma("unroll")                                                          \
    for (int ksl = 0; ksl < 2; ++ksl) {                                        \
        _Pragma("unroll")                                                      \
        for (int ns = 0; ns < NCB; ++ns) {                                     \
            int n_ = ns * 16 + r16;                                            \
            int byte_ = (n_ << 7) + (ksl << 6) + (kg << 4);                    \
            byte_ ^= (n_ & 7) << 4;                                            \
            bf16x8 bfr_ = *(const bf16x8*)((const char*)(BUF) + byte_);        \
            acc[ns] = __builtin_amdgcn_mfma_f32_16x16x32_bf16(                 \
                a[(Q) * 2 + ksl], bfr_, acc[ns], 0, 0, 0);                     \
        }                                                                      \
    }                                                                          \
} while (0)

// gemm17 (champion, round-17 exact): gemm11 + NT stores + 5 blocks/CU.
__launch_bounds__(256, 5)
__global__ void moe_gemm17_k(const short* __restrict__ thsort,
                             const float* __restrict__ megab,
                             const int* __restrict__ wsi,
                             const short* __restrict__ wbf,
                             float* __restrict__ out) {
    __shared__ char Bs[LDS_BYTES];

    int Bid = blockIdx.x;
    const int q8 = G_BLOCKS / 8, r8 = G_BLOCKS % 8;   // 232, 6
    int xcd = Bid & 7, slot = Bid >> 3;
    int w = (xcd < r8 ? xcd * (q8 + 1) : r8 * (q8 + 1) + (xcd - r8) * q8) + slot;
    int mt = w / NCB, cb = w % NCB;

    int total = wsi[24];
    if (mt >= total) return;

    int d = wsi[WS_DESC + mt];
    int startRow = d & 0x3FFF;
    int rc = (d >> 14) & 0x7F;
    int g  = d >> 21;

    int tid = threadIdx.x;
    int wv = tid >> 6, l = tid & 63, r16 = l & 15, kg = l >> 4;

    const char* Wcb = (const char*)(wbf + ((size_t)g * DIM_OUT + (size_t)cb * BN) * DIM_IN);

    stage_q(Wcb, 0, Bs, tid);
    stage_q(Wcb, 1, Bs + QB, tid);

    int mloc = wv * 16 + r16; if (mloc >= rc) mloc = rc - 1;
    const short* Ar = thsort + (size_t)(startRow + mloc) * DIM_IN + kg * 8;
    bf16x8 a[8];
#pragma unroll
    for (int ks = 0; ks < 8; ++ks)
        a[ks] = *(const bf16x8*)(Ar + ks * 32);

    f32x4 acc[NCB];
#pragma unroll
    for (int ns = 0; ns < NCB; ++ns) acc[ns] = (f32x4){0.f, 0.f, 0.f, 0.f};

    __syncthreads();
    COMPUTE_Q(0, Bs);
    COMPUTE_Q(1, Bs + QB);
    __syncthreads();

    stage_q(Wcb, 2, Bs, tid);
    stage_q(Wcb, 3, Bs + QB, tid);
    __syncthreads();
    COMPUTE_Q(2, Bs);
    COMPUTE_Q(3, Bs + QB);

    const float* bg = megab + (size_t)g * DIM_OUT + (size_t)cb * BN;

    __syncthreads();

    float* rowbuf = (float*)Bs + wv * (16 * RBSTRIDE);
#pragma unroll
    for (int ns = 0; ns < NCB; ++ns) {
        int nloc = ns * 16 + r16;
        float bias = bg[nloc];
#pragma unroll
        for (int j = 0; j < 4; ++j) {
            float x = acc[ns][j] + bias;
            rowbuf[(kg * 4 + j) * RBSTRIDE + nloc] = 1.0f / (1.0f + __expf(-x));
        }
    }

    __syncthreads();

    const int* idxw = wsi + WS_IDX + startRow + wv * 16;
#pragma unroll
    for (int t = 0; t < 7; ++t) {
        int c = t * 64 + l;
        int row = c / 28;
        int cir = c - row * 28;
        if (wv * 16 + row < rc) {
            f32x4 v = *(const f32x4*)(rowbuf + row * RBSTRIDE + cir * 4);
            int orow = idxw[row];
            __builtin_nontemporal_store(v,
                (f32x4*)(out + (size_t)orow * DIM_OUT + cb * BN + cir * 4));
        }
    }
}

// =============== fallback path (needs only wbf; r4-proven) ===============
__global__ void prep_k(const float* __restrict__ megaW,
                       const int* __restrict__ label,
                       int* __restrict__ wsi,
                       short* __restrict__ wbf) {
    int b = blockIdx.x, t = threadIdx.x;
    if (b < 980) {
        int base = b * 2048 + t * 8;
        f32x4 v0 = *(const f32x4*)(megaW + base);
        f32x4 v1 = *(const f32x4*)(megaW + base + 4);
        bf16x8 o;
        o[0] = f2bf(v0[0]); o[1] = f2bf(v0[1]); o[2] = f2bf(v0[2]); o[3] = f2bf(v0[3]);
        o[4] = f2bf(v1[0]); o[5] = f2bf(v1[1]); o[6] = f2bf(v1[2]); o[7] = f2bf(v1[3]);
        *(bf16x8*)(wbf + base) = o;
    } else {
        __shared__ int h[NDIGIT];
        int j = b - 980;
        if (t < NDIGIT) h[t] = 0;
        __syncthreads();
        int i0 = j * 512;
        atomicAdd(&h[label[i0 + t]], 1);
        atomicAdd(&h[label[i0 + 256 + t]], 1);
        __syncthreads();
        if (t < NDIGIT) wsi[64 + j * 16 + t] = h[t];
    }
}

__launch_bounds__(256, 4)
__global__ void moe_gemm4_k(const float* __restrict__ theta,
                            const float* __restrict__ megab,
                            const int* __restrict__ wsi,
                            const short* __restrict__ wbf,
                            float* __restrict__ out) {
    __shared__ short Bsf[BN * 128];
    int Bid = blockIdx.x;
    const int q8 = G_BLOCKS / 8, r8 = G_BLOCKS % 8;
    int xcd = Bid & 7, slot = Bid >> 3;
    int w = (xcd < r8 ? xcd * (q8 + 1) : r8 * (q8 + 1) + (xcd - r8) * q8) + slot;
    int mt = w / NCB, cb = w % NCB;
    int total = wsi[24];
    if (mt >= total) return;
    int g = 0;
    while (mt >= wsi[12 + g + 1]) ++g;
    int lt    = mt - wsi[12 + g];
    int start = wsi[g];
    int cnt   = wsi[g + 1] - start;
    int row0  = lt * BM;
    int rc    = min(BM, cnt - row0);
    int tid = threadIdx.x;
    int wv = tid >> 6, l = tid & 63, r16 = l & 15, kg = l >> 4;
    const char* Wcb = (const char*)(wbf + ((size_t)g * DIM_OUT + (size_t)cb * BN) * DIM_IN);
#pragma unroll
    for (int it = 0; it < 7; ++it) {
        int lbyte = (it * 256 + tid) << 4;
        int L = lbyte ^ (((lbyte >> 8) & 7) << 4);
        int srcoff = ((L >> 8) << 9) + (L & 255);
        gload16(Wcb + srcoff, (char*)Bsf + lbyte);
    }
    const int* idxlist = wsi + WS_IDX + start + row0;
    int mloc = wv * 16 + r16;
    int asrc = (mloc < rc) ? idxlist[mloc] : idxlist[0];
    const float* Arow = theta + (size_t)asrc * DIM_IN;
    bf16x8 a[8];
#pragma unroll
    for (int ks = 0; ks < 8; ++ks) {
        int k0 = ks * 32 + kg * 8;
        f32x4 v0 = *(const f32x4*)(Arow + k0);
        f32x4 v1 = *(const f32x4*)(Arow + k0 + 4);
        bf16x8 af;
        af[0] = f2bf(v0[0]); af[1] = f2bf(v0[1]);
        af[2] = f2bf(v0[2]); af[3] = f2bf(v0[3]);
        af[4] = f2bf(v1[0]); af[5] = f2bf(v1[1]);
        af[6] = f2bf(v1[2]); af[7] = f2bf(v1[3]);
        a[ks] = af;
    }
    f32x4 acc[NCB];
#pragma unroll
    for (int ns = 0; ns < NCB; ++ns) acc[ns] = (f32x4){0.f, 0.f, 0.f, 0.f};
    __syncthreads();
#pragma unroll
    for (int ks = 0; ks < 4; ++ks)
#pragma unroll
        for (int ns = 0; ns < NCB; ++ns) {
            int n = ns * 16 + r16;
            int byte = (n << 8) + (ks << 6) + (kg << 4);
            byte ^= (n & 7) << 4;
            bf16x8 b = *(const bf16x8*)((const char*)Bsf + byte);
            acc[ns] = __builtin_amdgcn_mfma_f32_16x16x32_bf16(a[ks], b, acc[ns], 0, 0, 0);
        }
    __syncthreads();
#pragma unroll
    for (int it = 0; it < 7; ++it) {
        int lbyte = (it * 256 + tid) << 4;
        int L = lbyte ^ (((lbyte >> 8) & 7) << 4);
        int srcoff = ((L >> 8) << 9) + (L & 255) + 256;
        gload16(Wcb + srcoff, (char*)Bsf + lbyte);
    }
    __syncthreads();
#pragma unroll
    for (int ks = 0; ks < 4; ++ks)
#pragma unroll
        for (int ns = 0; ns < NCB; ++ns) {
            int n = ns * 16 + r16;
            int byte = (n << 8) + (ks << 6) + (kg << 4);
            byte ^= (n & 7) << 4;
            bf16x8 b = *(const bf16x8*)((const char*)Bsf + byte);
            acc[ns] = __builtin_amdgcn_mfma_f32_16x16x32_bf16(a[4 + ks], b, acc[ns], 0, 0, 0);
        }
    const float* bg = megab + (size_t)g * DIM_OUT + (size_t)cb * BN;
    int rbase = wv * 16 + kg * 4;
    int orow[4];
#pragma unroll
    for (int j = 0; j < 4; ++j)
        orow[j] = (rbase + j < rc) ? idxlist[rbase + j] : -1;
#pragma unroll
    for (int ns = 0; ns < NCB; ++ns) {
        int nloc = ns * 16 + r16;
        float bias = bg[nloc];
#pragma unroll
        for (int j = 0; j < 4; ++j) {
            if (orow[j] >= 0) {
                float x = acc[ns][j] + bias;
                out[(size_t)orow[j] * DIM_OUT + cb * BN + nloc] = 1.0f / (1.0f + __expf(-x));
            }
        }
    }
}

extern "C" void kernel_launch(void* const* d_in, const int* in_sizes, int n_in,
                              void* d_out, int out_size, void* d_ws, size_t ws_size,
                              hipStream_t stream) {
    const float* theta = (const float*)d_in[0];
    const int*   label = (const int*)d_in[1];
    const float* megaW = (const float*)d_in[2];
    const float* megab = (const float*)d_in[3];
    float* out = (float*)d_out;
    int* wsi = (int*)d_ws;
    short* wbf = (short*)((char*)d_ws + WS_WBF_BYTES);

    if (ws_size >= (size_t)WS_NEED) {
        short* thsort = (short*)((char*)d_ws + WS_TH_BYTES);
        hist_k      <<<32, 256, 0, stream>>>(label, wsi);
        scatter2_k  <<<32, 512, 0, stream>>>(label, wsi);
        gw_k        <<<3028, 256, 0, stream>>>(theta, megaW, wsi, thsort, wbf);
        moe_gemm17_k<<<G_BLOCKS, 256, 0, stream>>>(thsort, megab, wsi, wbf, out);
    } else {
        prep_k     <<<1012, 256, 0, stream>>>(megaW, label, wsi, wbf);
        scatter2_k <<<32, 512, 0, stream>>>(label, wsi);
        moe_gemm4_k<<<G_BLOCKS, 256, 0, stream>>>(theta, megab, wsi, wbf, out);
    }
}